// Round 8
// baseline (560.398 us; speedup 1.0000x reference)
//
#include <hip/hip_runtime.h>
#include <hip/hip_fp16.h>

#define IN_F 24
#define HID 64
#define BLKN 1024   // nodes per scan block

typedef unsigned int u32;

// ---------------- R8 direct-atomic CSR build ----------------
// R0-R7 used a 5-kernel two-level bucket sort (no device-scope atomics). R8 theory:
// neighbor order within a CSR row is irrelevant (sum), so build directly:
// hist (fire-forget atomics, L2-resident 400KB) -> 3-kernel scan (+dinv+xs pack fused)
// -> scatter (returning atomic per edge). Cuts edge-stream traffic 77->51 MB and
// removes the pairs buffer + per-bucket LDS machinery entirely.

__global__ __launch_bounds__(1024) void k_hist(const int* __restrict__ dst,
                                               u32* __restrict__ cnt, int e) {
    int i = blockIdx.x * 1024 + threadIdx.x;
    if (i < e) atomicAdd(&cnt[dst[i]], 1u);
}

// scan_a: 256 threads/block, 4 nodes/thread (BLKN=1024 nodes/block) -> partial excl + block sums
__global__ __launch_bounds__(256) void k_scan_a(const u32* __restrict__ cnt,
                                                u32* __restrict__ rs,
                                                u32* __restrict__ bsum, int n) {
    __shared__ u32 s[256];
    int b = blockIdx.x;
    int t = threadIdx.x;
    int base = b * BLKN + t * 4;
    u32 c0 = 0, c1 = 0, c2 = 0, c3 = 0;
    if (base + 3 < n) {
        uint4 v = *(const uint4*)(cnt + base);
        c0 = v.x; c1 = v.y; c2 = v.z; c3 = v.w;
    } else {
        if (base + 0 < n) c0 = cnt[base + 0];
        if (base + 1 < n) c1 = cnt[base + 1];
        if (base + 2 < n) c2 = cnt[base + 2];
        if (base + 3 < n) c3 = cnt[base + 3];
    }
    u32 tsum = c0 + c1 + c2 + c3;
    s[t] = tsum;
    __syncthreads();
    for (int off = 1; off < 256; off <<= 1) {
        u32 v2 = (t >= off) ? s[t - off] : 0;
        __syncthreads();
        s[t] += v2;
        __syncthreads();
    }
    u32 excl = s[t] - tsum;
    u32 p0 = excl, p1 = excl + c0, p2 = p1 + c1, p3 = p2 + c2;
    if (base + 3 < n) {
        *(uint4*)(rs + base) = make_uint4(p0, p1, p2, p3);
    } else {
        if (base + 0 < n) rs[base + 0] = p0;
        if (base + 1 < n) rs[base + 1] = p1;
        if (base + 2 < n) rs[base + 2] = p2;
        if (base + 3 < n) rs[base + 3] = p3;
    }
    if (t == 255) bsum[b] = s[255];
}

// scan_b: exclusive scan of the <=128 block sums (n=100k -> 98 blocks)
__global__ void k_scan_b(u32* __restrict__ bsum, int nb) {
    __shared__ u32 s[128];
    int t = threadIdx.x;
    u32 v = (t < nb) ? bsum[t] : 0;
    s[t] = v;
    __syncthreads();
    for (int off = 1; off < 128; off <<= 1) {
        u32 v2 = (t >= off) ? s[t - off] : 0;
        __syncthreads();
        s[t] += v2;
        __syncthreads();
    }
    if (t < nb) bsum[t] = s[t] - v;
}

// scan_c: finalize row_start (+block offset), init scatter cursor, dinv, fused xs f16 pack
__global__ __launch_bounds__(256) void k_scan_c(const u32* __restrict__ cnt,
                                                u32* __restrict__ rs,
                                                const u32* __restrict__ bsum,
                                                u32* __restrict__ cur,
                                                float* __restrict__ dinv,
                                                const float* __restrict__ x,
                                                __half2* __restrict__ xs2, int n) {
    __shared__ float dloc[BLKN];
    int b = blockIdx.x;
    u32 off = bsum[b];
    int lo = b * BLKN;
    int cnt_here = n - lo;
    if (cnt_here > BLKN) cnt_here = BLKN;
    for (int i = threadIdx.x; i < cnt_here; i += 256) {
        int node = lo + i;
        u32 r = rs[node] + off;
        rs[node] = r;          // final row_start
        cur[node] = r;         // scatter cursor = row_start (absolute positions)
        float dv = rsqrtf((float)(cnt[node] + 1));  // +1 self-loop
        dinv[node] = dv;
        dloc[i] = dv;
    }
    __syncthreads();
    // pack xs[i][f] = f16(x[i][f] * dinv[i]), 48-B rows, coalesced float2 loop
    const float2* xf = (const float2*)(x + (long long)lo * IN_F);
    int tot = cnt_here * 12;
    for (int i = threadIdx.x; i < tot; i += 256) {
        float2 vv = xf[i];
        float dn = dloc[i / 12];
        xs2[(long long)lo * 12 + i] = __floats2half2_rn(vv.x * dn, vv.y * dn);
    }
    // zero sentinel row at index n (masked final-batch slots in k_agg_hz)
    if (b == 0 && threadIdx.x < 12)
        xs2[(long long)n * 12 + threadIdx.x] = __floats2half2_rn(0.0f, 0.0f);
}

// scatter: pos = cur[d]++ (device atomic, L2-resident counters); csr[pos] = src
__global__ __launch_bounds__(1024) void k_scatter(const int* __restrict__ src,
                                                  const int* __restrict__ dst,
                                                  u32* __restrict__ cur,
                                                  int* __restrict__ csr_src, int e) {
    int i = blockIdx.x * 1024 + threadIdx.x;
    if (i < e) {
        int d = dst[i];
        int s = src[i];
        u32 pos = atomicAdd(&cur[d], 1u);
        csr_src[pos] = s;
    }
}

// ---------------- fused layer-1 aggregate + transform + layer-2 lin (barrier-free) ----------------
// R3 structure (8-lane groups, uint2 gathers) + R6 masked sentinel tail. Best measured.
__global__ __launch_bounds__(256) void k_agg_hz(const float* __restrict__ x,
                                                const __half2* __restrict__ xs2,
                                                const float* __restrict__ dinv,
                                                const int* __restrict__ row_start,
                                                const int* __restrict__ cnt,
                                                const int* __restrict__ csr_src,
                                                const float* __restrict__ W1,
                                                const float* __restrict__ b1,
                                                const float* __restrict__ W2,
                                                float* __restrict__ zs, int n) {
    __shared__ float w[IN_F * HID];   // k-major: w[k*64+f]
    __shared__ float w2s[HID];
    __shared__ float b1s[HID];
    for (int j = threadIdx.x; j < IN_F * HID; j += 256) w[j] = W1[j];
    if (threadIdx.x < HID) { w2s[threadIdx.x] = W2[threadIdx.x]; b1s[threadIdx.x] = b1[threadIdx.x]; }
    __syncthreads();   // weights only; no further barriers
    int g = threadIdx.x >> 3;        // 32 groups of 8 lanes
    int f4 = threadIdx.x & 7;        // 0..7; gather-active: 0..5
    int node = blockIdx.x * 32 + g;
    if (node >= n) return;
    float dn = dinv[node];
    const uint2* xq = (const uint2*)xs2;   // row r -> xq[r*6 + f4], 48 B rows
    // ---- Phase A: gather-aggregate into registers (lanes 0..5 of each group) ----
    float ax0 = 0.0f, ay0 = 0.0f, ax1 = 0.0f, ay1 = 0.0f;
    if (f4 < 6) {
        int row = row_start[node];
        int c = cnt[node];
        // 8 independent accumulator chains (even/odd slots)
        float a0 = 0.0f, b0 = 0.0f, c0 = 0.0f, d0 = 0.0f;
        float a1 = 0.0f, b1v = 0.0f, c1 = 0.0f, d1 = 0.0f;
        int j = 0;
        for (; j + 16 <= c; j += 16) {
            const int* cp = csr_src + row + j;
            int s[16];
#pragma unroll
            for (int t = 0; t < 16; ++t) s[t] = cp[t];
            uint2 u[16];
#pragma unroll
            for (int t = 0; t < 16; ++t) u[t] = xq[(size_t)((u32)s[t] * 6u + (u32)f4)];
#pragma unroll
            for (int t = 0; t < 16; t += 2) {
                float2 e0 = __half22float2(__builtin_bit_cast(__half2, u[t].x));
                float2 e1 = __half22float2(__builtin_bit_cast(__half2, u[t].y));
                float2 o0 = __half22float2(__builtin_bit_cast(__half2, u[t + 1].x));
                float2 o1 = __half22float2(__builtin_bit_cast(__half2, u[t + 1].y));
                a0 += e0.x; b0 += e0.y; c0 += e1.x; d0 += e1.y;
                a1 += o0.x; b1v += o0.y; c1 += o1.x; d1 += o1.y;
            }
        }
        if (j < c) {   // masked final batch: sentinel row n absorbs t >= rem slots
            const int* cp = csr_src + row + j;   // over-read <=15 ints lands in xs region (in-workspace)
            int rem = c - j;                      // 1..15
            int s[16];
#pragma unroll
            for (int t = 0; t < 16; ++t) {
                int tmp = cp[t];
                s[t] = (t < rem) ? tmp : n;
            }
            uint2 u[16];
#pragma unroll
            for (int t = 0; t < 16; ++t) u[t] = xq[(size_t)((u32)s[t] * 6u + (u32)f4)];
#pragma unroll
            for (int t = 0; t < 16; t += 2) {
                float2 e0 = __half22float2(__builtin_bit_cast(__half2, u[t].x));
                float2 e1 = __half22float2(__builtin_bit_cast(__half2, u[t].y));
                float2 o0 = __half22float2(__builtin_bit_cast(__half2, u[t + 1].x));
                float2 o1 = __half22float2(__builtin_bit_cast(__half2, u[t + 1].y));
                a0 += e0.x; b0 += e0.y; c0 += e1.x; d0 += e1.y;
                a1 += o0.x; b1v += o0.y; c1 += o1.x; d1 += o1.y;
            }
        }
        ax0 = a0 + a1; ay0 = b0 + b1v; ax1 = c0 + c1; ay1 = d0 + d1;
        // self-loop (float4: feats 4f4..4f4+3, 16-B aligned)
        float4 sx4 = *(const float4*)(x + (long long)node * IN_F + 4 * f4);
        ax0 = (ax0 + sx4.x * dn) * dn;
        ay0 = (ay0 + sx4.y * dn) * dn;
        ax1 = (ax1 + sx4.z * dn) * dn;
        ay1 = (ay1 + sx4.w * dn) * dn;
    }
    // ---- Phase B: dense transform; feats broadcast via width-8 shuffle ----
    int fb = f4 * 8;                  // 8 hidden units per lane (8 lanes x 8 = 64)
    float h[8];
#pragma unroll
    for (int jj = 0; jj < 8; ++jj) h[jj] = b1s[fb + jj];
#pragma unroll
    for (int k = 0; k < IN_F; ++k) {
        int sl = k >> 2;              // source lane 0..5
        int r = k & 3;
        float xv;
        if (r == 0)      xv = __shfl(ax0, sl, 8);
        else if (r == 1) xv = __shfl(ay0, sl, 8);
        else if (r == 2) xv = __shfl(ax1, sl, 8);
        else             xv = __shfl(ay1, sl, 8);
        const float* wr = w + k * HID + fb;
#pragma unroll
        for (int jj = 0; jj < 8; ++jj) h[jj] += xv * wr[jj];
    }
    float p = 0.0f;
#pragma unroll
    for (int jj = 0; jj < 8; ++jj) p += fmaxf(h[jj], 0.0f) * w2s[fb + jj];
    p += __shfl_down(p, 4, 8);
    p += __shfl_down(p, 2, 8);
    p += __shfl_down(p, 1, 8);
    if (f4 == 0) zs[node] = p * dn;
}

// ---------------- layer 2 gather: 16-lane group per node ----------------
__global__ void k_out(const float* __restrict__ zs, const float* __restrict__ dinv,
                      const int* __restrict__ row_start, const int* __restrict__ cnt,
                      const int* __restrict__ csr_src, const float* __restrict__ b2,
                      float* __restrict__ out, int n) {
    int t = blockIdx.x * blockDim.x + threadIdx.x;
    int node = t >> 4;
    int lane = t & 15;
    if (node >= n) return;
    int row = row_start[node];
    int c = cnt[node];
    float v = 0.0f;
    for (int j = lane; j < c; j += 16) {
        v += zs[csr_src[row + j]];
    }
    v += __shfl_down(v, 8, 16);
    v += __shfl_down(v, 4, 16);
    v += __shfl_down(v, 2, 16);
    v += __shfl_down(v, 1, 16);
    if (lane == 0) {
        out[node] = b2[0] + dinv[node] * (zs[node] + v);
    }
}

extern "C" void kernel_launch(void* const* d_in, const int* in_sizes, int n_in,
                              void* d_out, int out_size, void* d_ws, size_t ws_size,
                              hipStream_t stream) {
    const float* x   = (const float*)d_in[0];
    const int*   ei  = (const int*)d_in[1];
    const float* W1  = (const float*)d_in[2];
    const float* b1  = (const float*)d_in[3];
    const float* W2  = (const float*)d_in[4];
    const float* b2  = (const float*)d_in[5];
    float* out = (float*)d_out;

    const int n = in_sizes[0] / IN_F;      // 100000
    const int e = in_sizes[1] / 2;         // 3200000
    const int* src = ei;
    const int* dst = ei + e;

    // workspace layout (R8: no pairs buffer; ~20 MB total)
    char* base = (char*)d_ws;
    u32* cnt       = (u32*)base;                        // n u32 (memset to 0 each launch)
    u32* cur       = cnt + n;                           // n u32 (scatter cursors)
    u32* row_start = cur + n;                           // n u32
    float* dinv    = (float*)(row_start + n);           // n f32
    float* zs      = dinv + n;                          // n f32
    u32* bsum      = (u32*)(zs + n);                    // 128 u32 (scan block sums)
    int* csr_src   = (int*)(bsum + 128);                // e ints (12.8 MB)
    __half* xs     = (__half*)(csr_src + e);            // (n+1)*24 f16 (4.8 MB), sentinel row at n

    const int nscan = (n + BLKN - 1) / BLKN;            // 98 scan blocks (<=128)

    hipMemsetAsync(cnt, 0, (size_t)n * sizeof(u32), stream);
    k_hist<<<(e + 1023) / 1024, 1024, 0, stream>>>(dst, cnt, e);
    k_scan_a<<<nscan, 256, 0, stream>>>(cnt, row_start, bsum, n);
    k_scan_b<<<1, 128, 0, stream>>>(bsum, nscan);
    k_scan_c<<<nscan, 256, 0, stream>>>(cnt, row_start, bsum, cur, dinv, x,
                                        (__half2*)xs, n);
    k_scatter<<<(e + 1023) / 1024, 1024, 0, stream>>>(src, dst, cur, csr_src, e);

    // fused layer-1 aggregate + transform (+ layer-2 linear) -> zs (barrier-free)
    k_agg_hz<<<(n + 31) / 32, 256, 0, stream>>>(x, (const __half2*)xs, dinv,
                                                (const int*)row_start, (const int*)cnt,
                                                csr_src, W1, b1, W2, zs, n);

    // layer 2: gather zs (16 lanes/node)
    const long long n16 = (long long)n * 16;
    k_out<<<(int)((n16 + 255) / 256), 256, 0, stream>>>(zs, dinv, (const int*)row_start,
                                                        (const int*)cnt, csr_src, b2, out, n);
}

// Round 10
// 187.997 us; speedup vs baseline: 2.9809x; 2.9809x over previous
//
#include <hip/hip_runtime.h>
#include <hip/hip_fp16.h>

#define IN_F 24
#define HID 64
#define NB 512      // dst buckets (node ranges)
#define NPB 512     // partition blocks (edge slices) — R9: 2 blocks/CU (was 256)
#define GSZ_MAX 256 // max nodes per bucket (ceil(100000/512) = 196)
#define PBUF 7168   // pair capacity per bucket in LDS (mean ~6250, +11 sigma)
#define SRC_BITS 17 // src < 100000 < 2^17; loc < 196 < 2^8

typedef unsigned int u32;

// R8 post-mortem: direct-atomic CSR build REGRESSED 195->560us. k_scatter's random
// 4-B writes cost a 64-B line each (WRITE_SIZE 194 MB vs 12.8 logical, 15x amplification).
// The two-level bucket sort's extra pass is what buys sequential-per-bucket write
// locality -> keep it. R9: push R7's proven occupancy lever one notch further.

// bucket of node d:  k = floor(d*NB/n)
// node range of bucket b (exact inverse):  [ceil(b*n/NB), ceil((b+1)*n/NB))
__device__ __forceinline__ int bucket_lo(int b, int n) {
    return (int)(((long long)b * n + NB - 1) / NB);
}

// ---------------- pass 1a: per-(slice,bucket) histogram ----------------
__global__ __launch_bounds__(1024) void k_pcount(const int* __restrict__ dst,
                                                 u32* __restrict__ pc, int e, int n) {
    __shared__ u32 h[NB];
    for (int j = threadIdx.x; j < NB; j += 1024) h[j] = 0;
    __syncthreads();
    int blk = blockIdx.x;
    long long begin = (long long)e * blk / NPB;
    long long end   = (long long)e * (blk + 1) / NPB;
    for (long long i = begin + threadIdx.x; i < end; i += 1024) {
        int k = (int)((long long)dst[i] * NB / n);
        atomicAdd(&h[k], 1u);
    }
    __syncthreads();
    for (int j = threadIdx.x; j < NB; j += 1024) pc[(size_t)blk * NB + j] = h[j];
}

// ---------------- pass 1b-parallel: per-column exclusive scan (NPB=512 rows, 2/thread) ----------------
__global__ __launch_bounds__(256) void k_pscan_a(u32* __restrict__ pc,
                                                 u32* __restrict__ colsum) {
    __shared__ u32 ps[256];
    int t = blockIdx.x;   // column (bucket)
    int tid = threadIdx.x;
    u32 v0 = pc[(size_t)(2 * tid) * NB + t];
    u32 v1 = pc[(size_t)(2 * tid + 1) * NB + t];
    u32 tsum = v0 + v1;
    ps[tid] = tsum;
    __syncthreads();
    for (int off = 1; off < 256; off <<= 1) {
        u32 v2 = (tid >= off) ? ps[tid - off] : 0;
        __syncthreads();
        ps[tid] += v2;
        __syncthreads();
    }
    u32 excl = ps[tid] - tsum;
    pc[(size_t)(2 * tid) * NB + t] = excl;           // exclusive within-column
    pc[(size_t)(2 * tid + 1) * NB + t] = excl + v0;
    if (tid == 255) colsum[t] = ps[255];
}

// exclusive scan of the 512 column sums -> bucket bases
__global__ void k_pscan_b(const u32* __restrict__ colsum, u32* __restrict__ basep) {
    __shared__ u32 s[NB];
    int t = threadIdx.x;
    u32 v = colsum[t];
    s[t] = v;
    __syncthreads();
    for (int off = 1; off < NB; off <<= 1) {
        u32 v2 = (t >= off) ? s[t - off] : 0;
        __syncthreads();
        s[t] += v2;
        __syncthreads();
    }
    basep[t] = s[t] - v;
}

// ---------------- pass 1c: direct scatter of packed (loc<<17|src) into bucket order ----------------
__global__ __launch_bounds__(1024) void k_part(const int* __restrict__ src,
                                               const int* __restrict__ dst,
                                               const u32* __restrict__ pc,
                                               const u32* __restrict__ basep,
                                               u32* __restrict__ pairs, int e, int n) {
    __shared__ u32 cur[NB];
    int blk = (blockIdx.x & 7) * (NPB / 8) + (blockIdx.x >> 3);  // XCD-affine (perf heuristic)
    for (int j = threadIdx.x; j < NB; j += 1024)
        cur[j] = pc[(size_t)blk * NB + j] + basep[j];
    __syncthreads();
    long long begin = (long long)e * blk / NPB;
    long long end   = (long long)e * (blk + 1) / NPB;
    for (long long i = begin + threadIdx.x; i < end; i += 1024) {
        int d = dst[i];
        int sv = src[i];
        int k = (int)((long long)d * NB / n);
        u32 loc = (u32)(d - bucket_lo(k, n));
        u32 pos = atomicAdd(&cur[k], 1u);
        pairs[pos] = (loc << SRC_BITS) | (u32)sv;
    }
}

// ---------------- pass 2: per-bucket mini-CSR in LDS (+ fused xs f16 pack, 48 B rows) ----------------
// R9: 1024-thread blocks (LDS 33 KB -> 2 blocks/CU = 32 waves/CU; scan guarded to 256 lanes).
__global__ __launch_bounds__(1024) void k_bucket(const u32* __restrict__ pairs,
                                                 const u32* __restrict__ basep,
                                                 const float* __restrict__ x,
                                                 int* __restrict__ cnt,
                                                 int* __restrict__ row_start,
                                                 float* __restrict__ dinv,
                                                 int* __restrict__ csr_src,
                                                 __half2* __restrict__ xs2, int e, int n) {
    __shared__ u32 pbuf[PBUF];
    __shared__ u32 h[GSZ_MAX];
    __shared__ u32 cur[GSZ_MAX];
    __shared__ u32 sc[GSZ_MAX];
    __shared__ float dloc[GSZ_MAX];
    int b = blockIdx.x;
    // zero sentinel row at index n (read by masked final-batch slots in k_agg_hz)
    if (b == 0 && threadIdx.x < 12)
        xs2[(long long)n * 12 + threadIdx.x] = __floats2half2_rn(0.0f, 0.0f);
    int lo = bucket_lo(b, n);
    int hi = bucket_lo(b + 1, n);
    int gsz = hi - lo;               // <= GSZ_MAX
    u32 start = basep[b];
    u32 endp = (b + 1 < NB) ? basep[b + 1] : (u32)e;
    int nbp = (int)(endp - start);
    for (int j = threadIdx.x; j < GSZ_MAX; j += 1024) h[j] = 0;
    __syncthreads();
    int stored = nbp < PBUF ? nbp : PBUF;
    for (int i = threadIdx.x; i < stored; i += 1024) {
        u32 p = pairs[start + i];
        pbuf[i] = p;
        atomicAdd(&h[p >> SRC_BITS], 1u);
    }
    for (int i = PBUF + threadIdx.x; i < nbp; i += 1024) {  // overflow path (rare)
        atomicAdd(&h[pairs[start + i] >> SRC_BITS], 1u);
    }
    __syncthreads();
    int t = threadIdx.x;
    u32 v = 0;
    if (t < GSZ_MAX) { v = h[t]; sc[t] = v; }
    __syncthreads();
    for (int off = 1; off < GSZ_MAX; off <<= 1) {
        u32 v2 = (t >= off && t < GSZ_MAX) ? sc[t - off] : 0;
        __syncthreads();
        if (t < GSZ_MAX) sc[t] += v2;
        __syncthreads();
    }
    u32 excl = (t < GSZ_MAX) ? (sc[t] - v) : 0;
    if (t < gsz) {
        float dv = rsqrtf((float)(v + 1));  // +1 self-loop
        cnt[lo + t] = (int)v;
        row_start[lo + t] = (int)(start + excl);
        dinv[lo + t] = dv;
        dloc[t] = dv;
        cur[t] = excl;
    }
    __syncthreads();
    for (int i = threadIdx.x; i < stored; i += 1024) {
        u32 p = pbuf[i];
        u32 pos = atomicAdd(&cur[p >> SRC_BITS], 1u);
        csr_src[start + pos] = (int)(p & ((1u << SRC_BITS) - 1));
    }
    for (int i = PBUF + threadIdx.x; i < nbp; i += 1024) {
        u32 p = pairs[start + i];
        u32 pos = atomicAdd(&cur[p >> SRC_BITS], 1u);
        csr_src[start + pos] = (int)(p & ((1u << SRC_BITS) - 1));
    }
    // fused pack: xs[i][f] = f16(x[i][f] * dinv[i]) for this bucket's nodes (contiguous)
    const float2* xf = (const float2*)(x + (long long)lo * IN_F);
    for (int i = threadIdx.x; i < gsz * 12; i += 1024) {
        float2 vv = xf[i];
        float dn = dloc[i / 12];
        xs2[(long long)lo * 12 + i] = __floats2half2_rn(vv.x * dn, vv.y * dn);
    }
}

// ---------------- fused layer-1 aggregate + transform + layer-2 lin (barrier-free) ----------------
// R3 structure (8-lane groups, uint2 gathers) + R6 masked sentinel tail. Best measured.
__global__ __launch_bounds__(256) void k_agg_hz(const float* __restrict__ x,
                                                const __half2* __restrict__ xs2,
                                                const float* __restrict__ dinv,
                                                const int* __restrict__ row_start,
                                                const int* __restrict__ cnt,
                                                const int* __restrict__ csr_src,
                                                const float* __restrict__ W1,
                                                const float* __restrict__ b1,
                                                const float* __restrict__ W2,
                                                float* __restrict__ zs, int n) {
    __shared__ float w[IN_F * HID];   // k-major: w[k*64+f]
    __shared__ float w2s[HID];
    __shared__ float b1s[HID];
    for (int j = threadIdx.x; j < IN_F * HID; j += 256) w[j] = W1[j];
    if (threadIdx.x < HID) { w2s[threadIdx.x] = W2[threadIdx.x]; b1s[threadIdx.x] = b1[threadIdx.x]; }
    __syncthreads();   // weights only; no further barriers
    int g = threadIdx.x >> 3;        // 32 groups of 8 lanes
    int f4 = threadIdx.x & 7;        // 0..7; gather-active: 0..5
    int node = blockIdx.x * 32 + g;
    if (node >= n) return;
    float dn = dinv[node];
    const uint2* xq = (const uint2*)xs2;   // row r -> xq[r*6 + f4], 48 B rows
    // ---- Phase A: gather-aggregate into registers (lanes 0..5 of each group) ----
    float ax0 = 0.0f, ay0 = 0.0f, ax1 = 0.0f, ay1 = 0.0f;
    if (f4 < 6) {
        int row = row_start[node];
        int c = cnt[node];
        // 8 independent accumulator chains (even/odd slots)
        float a0 = 0.0f, b0 = 0.0f, c0 = 0.0f, d0 = 0.0f;
        float a1 = 0.0f, b1v = 0.0f, c1 = 0.0f, d1 = 0.0f;
        int j = 0;
        for (; j + 16 <= c; j += 16) {
            const int* cp = csr_src + row + j;
            int s[16];
#pragma unroll
            for (int t = 0; t < 16; ++t) s[t] = cp[t];
            uint2 u[16];
#pragma unroll
            for (int t = 0; t < 16; ++t) u[t] = xq[(size_t)((u32)s[t] * 6u + (u32)f4)];
#pragma unroll
            for (int t = 0; t < 16; t += 2) {
                float2 e0 = __half22float2(__builtin_bit_cast(__half2, u[t].x));
                float2 e1 = __half22float2(__builtin_bit_cast(__half2, u[t].y));
                float2 o0 = __half22float2(__builtin_bit_cast(__half2, u[t + 1].x));
                float2 o1 = __half22float2(__builtin_bit_cast(__half2, u[t + 1].y));
                a0 += e0.x; b0 += e0.y; c0 += e1.x; d0 += e1.y;
                a1 += o0.x; b1v += o0.y; c1 += o1.x; d1 += o1.y;
            }
        }
        if (j < c) {   // masked final batch: sentinel row n absorbs t >= rem slots
            const int* cp = csr_src + row + j;   // over-read <=15 ints lands in-workspace
            int rem = c - j;                      // 1..15
            int s[16];
#pragma unroll
            for (int t = 0; t < 16; ++t) {
                int tmp = cp[t];
                s[t] = (t < rem) ? tmp : n;
            }
            uint2 u[16];
#pragma unroll
            for (int t = 0; t < 16; ++t) u[t] = xq[(size_t)((u32)s[t] * 6u + (u32)f4)];
#pragma unroll
            for (int t = 0; t < 16; t += 2) {
                float2 e0 = __half22float2(__builtin_bit_cast(__half2, u[t].x));
                float2 e1 = __half22float2(__builtin_bit_cast(__half2, u[t].y));
                float2 o0 = __half22float2(__builtin_bit_cast(__half2, u[t + 1].x));
                float2 o1 = __half22float2(__builtin_bit_cast(__half2, u[t + 1].y));
                a0 += e0.x; b0 += e0.y; c0 += e1.x; d0 += e1.y;
                a1 += o0.x; b1v += o0.y; c1 += o1.x; d1 += o1.y;
            }
        }
        ax0 = a0 + a1; ay0 = b0 + b1v; ax1 = c0 + c1; ay1 = d0 + d1;
        // self-loop (float4: feats 4f4..4f4+3, 16-B aligned)
        float4 sx4 = *(const float4*)(x + (long long)node * IN_F + 4 * f4);
        ax0 = (ax0 + sx4.x * dn) * dn;
        ay0 = (ay0 + sx4.y * dn) * dn;
        ax1 = (ax1 + sx4.z * dn) * dn;
        ay1 = (ay1 + sx4.w * dn) * dn;
    }
    // ---- Phase B: dense transform; feats broadcast via width-8 shuffle ----
    int fb = f4 * 8;                  // 8 hidden units per lane (8 lanes x 8 = 64)
    float h[8];
#pragma unroll
    for (int jj = 0; jj < 8; ++jj) h[jj] = b1s[fb + jj];
#pragma unroll
    for (int k = 0; k < IN_F; ++k) {
        int sl = k >> 2;              // source lane 0..5
        int r = k & 3;
        float xv;
        if (r == 0)      xv = __shfl(ax0, sl, 8);
        else if (r == 1) xv = __shfl(ay0, sl, 8);
        else if (r == 2) xv = __shfl(ax1, sl, 8);
        else             xv = __shfl(ay1, sl, 8);
        const float* wr = w + k * HID + fb;
#pragma unroll
        for (int jj = 0; jj < 8; ++jj) h[jj] += xv * wr[jj];
    }
    float p = 0.0f;
#pragma unroll
    for (int jj = 0; jj < 8; ++jj) p += fmaxf(h[jj], 0.0f) * w2s[fb + jj];
    p += __shfl_down(p, 4, 8);
    p += __shfl_down(p, 2, 8);
    p += __shfl_down(p, 1, 8);
    if (f4 == 0) zs[node] = p * dn;
}

// ---------------- layer 2 gather: 16-lane group per node ----------------
__global__ void k_out(const float* __restrict__ zs, const float* __restrict__ dinv,
                      const int* __restrict__ row_start, const int* __restrict__ cnt,
                      const int* __restrict__ csr_src, const float* __restrict__ b2,
                      float* __restrict__ out, int n) {
    int t = blockIdx.x * blockDim.x + threadIdx.x;
    int node = t >> 4;
    int lane = t & 15;
    if (node >= n) return;
    int row = row_start[node];
    int c = cnt[node];
    float v = 0.0f;
    for (int j = lane; j < c; j += 16) {
        v += zs[csr_src[row + j]];
    }
    v += __shfl_down(v, 8, 16);
    v += __shfl_down(v, 4, 16);
    v += __shfl_down(v, 2, 16);
    v += __shfl_down(v, 1, 16);
    if (lane == 0) {
        out[node] = b2[0] + dinv[node] * (zs[node] + v);
    }
}

extern "C" void kernel_launch(void* const* d_in, const int* in_sizes, int n_in,
                              void* d_out, int out_size, void* d_ws, size_t ws_size,
                              hipStream_t stream) {
    const float* x   = (const float*)d_in[0];
    const int*   ei  = (const int*)d_in[1];
    const float* W1  = (const float*)d_in[2];
    const float* b1  = (const float*)d_in[3];
    const float* W2  = (const float*)d_in[4];
    const float* b2  = (const float*)d_in[5];
    float* out = (float*)d_out;

    const int n = in_sizes[0] / IN_F;      // 100000
    const int e = in_sizes[1] / 2;         // 3200000
    const int* src = ei;
    const int* dst = ei + e;

    const int B = 256;

    // workspace layout. pairs (u32, CSR build) overlays zs (lifetimes disjoint).
    // xs written by k_bucket while other blocks still read pairs -> OUTSIDE the overlay.
    char* base = (char*)d_ws;
    u32* pairs     = (u32*)base;                        // e u32 (12.8 MB)
    float* zs      = (float*)base;                      // n f32              [overlay]
    size_t ov = ((size_t)e * 4 + 255) & ~(size_t)255;
    char* after    = base + ov;
    int* cnt       = (int*)after;
    int* row_start = cnt + n;
    int* csr_src   = row_start + n;                     // e ints (12.8 MB)
    float* dinv    = (float*)(csr_src + e);
    __half* xs     = (__half*)(dinv + n);               // (n+1)*24 f16 (4.8 MB), sentinel row at n
    u32* pc        = (u32*)(xs + (size_t)(n + 1) * IN_F); // NPB*NB u32 (1 MB)
    u32* colsum    = pc + (size_t)NPB * NB;             // NB u32
    u32* basep     = colsum + NB;                       // NB u32

    // CSR build: single-read two-level bucket sort (no device-scope atomics)
    k_pcount<<<NPB, 1024, 0, stream>>>(dst, pc, e, n);
    k_pscan_a<<<NB, B, 0, stream>>>(pc, colsum);
    k_pscan_b<<<1, NB, 0, stream>>>(colsum, basep);
    k_part<<<NPB, 1024, 0, stream>>>(src, dst, pc, basep, pairs, e, n);
    k_bucket<<<NB, 1024, 0, stream>>>(pairs, basep, x, cnt, row_start, dinv, csr_src,
                                      (__half2*)xs, e, n);

    // fused layer-1 aggregate + transform (+ layer-2 linear) -> zs (barrier-free)
    k_agg_hz<<<(n + 31) / 32, B, 0, stream>>>(x, (const __half2*)xs, dinv,
                                              row_start, cnt, csr_src,
                                              W1, b1, W2, zs, n);

    // layer 2: gather zs (16 lanes/node)
    const long long n16 = (long long)n * 16;
    k_out<<<(int)((n16 + B - 1) / B), B, 0, stream>>>(zs, dinv, row_start, cnt, csr_src, b2, out, n);
}